// Round 3
// baseline (990.550 us; speedup 1.0000x reference)
//
#include <hip/hip_runtime.h>

// Problem constants (fixed by the reference)
#define KS   5      // kernel size
#define DIL  2      // dilation
#define PAD  4      // (KS/2)*DIL
#define B_   4
#define C_   32
#define P_   8
#define OUTC 24     // DYNAMIC_SIZE
#define H_   512
#define W_   512
#define HW   (H_ * W_)
#define GPR  128    // 4-pixel groups per row (512/4)

typedef float4 f4;

// 4 consecutive x-pixels per thread. Fused per-row structure: for each of the
// 5 dy rows, compute the 5 x-tap range weights (d2 over 8 guide channels),
// then immediately accumulate all 24 channels with those weights. Only
// d2row[5]/w5[5] (20 VGPR) + acc[24] f4 (96 VGPR) live at once — no spills.
// Normalization by 1/(wsum+eps) applied once at the end (identical math).
__global__ __launch_bounds__(256, 3)
void bilateral_fused(const float* __restrict__ inp,   // (B, C, H, W)
                     const float* __restrict__ par,   // (B, P, H, W)
                     float* __restrict__ out)         // (B, OUTC, H, W)
{
    const int tid = blockIdx.x * blockDim.x + threadIdx.x;
    const int g  = tid & (GPR - 1);
    const int y  = (tid >> 7) & (H_ - 1);
    const int b  = tid >> 16;              // GPR*H_ = 65536 per batch
    const int x0 = g << 2;

    const float* __restrict__ parb = par + (size_t)b * P_ * HW;
    const float* __restrict__ inpb = inp + (size_t)b * C_ * HW;
    float* __restrict__ outb       = out + (size_t)b * OUTC * HW;

    // 3 chunk x-bases (4-aligned). OOB chunks are entirely outside the row and
    // feed only zero-weight taps, so clamping the address is safe.
    int cbx[3];
#pragma unroll
    for (int k = 0; k < 3; ++k) {
        const int xx = x0 + 4 * (k - 1);
        cbx[k] = min(max(xx, 0), W_ - 4);
    }
    const int crow = y * W_ + x0;

    f4 acc[OUTC];
#pragma unroll
    for (int c = 0; c < OUTC; ++c) acc[c] = make_float4(0.f, 0.f, 0.f, 0.f);
    f4 wsum = make_float4(0.f, 0.f, 0.f, 0.f);

#pragma unroll 1   // keep the dy loop rolled: bounds I$ and register live ranges
    for (int d = 0; d < KS; ++d) {
        const int yy  = y + d * DIL - PAD;
        const bool rok = (yy >= 0) & (yy < H_);
        const int roff = min(max(yy, 0), H_ - 1) * W_;

        // ---- range weights for this row: d2 over the 8 guide channels ----
        f4 d2r[KS];
#pragma unroll
        for (int e = 0; e < KS; ++e) d2r[e] = make_float4(0.f, 0.f, 0.f, 0.f);

#pragma unroll
        for (int p = 0; p < P_; ++p) {
            const float* __restrict__ pp = parb + p * HW;
            const f4 pc = *(const f4*)(pp + crow);     // center (L1-hot reload)
            float r[12];
#pragma unroll
            for (int k = 0; k < 3; ++k) {
                const f4 v = *(const f4*)(pp + roff + cbx[k]);
                r[4 * k + 0] = v.x; r[4 * k + 1] = v.y;
                r[4 * k + 2] = v.z; r[4 * k + 3] = v.w;
            }
#pragma unroll
            for (int e = 0; e < KS; ++e) {
                const float q0 = pc.x - r[2 * e + 0];
                const float q1 = pc.y - r[2 * e + 1];
                const float q2 = pc.z - r[2 * e + 2];
                const float q3 = pc.w - r[2 * e + 3];
                d2r[e].x += q0 * q0; d2r[e].y += q1 * q1;
                d2r[e].z += q2 * q2; d2r[e].w += q3 * q3;
            }
        }

        // ---- exp + mask ----
        const float rokf = rok ? 1.f : 0.f;
        f4 w5[KS];
#pragma unroll
        for (int e = 0; e < KS; ++e) {
            const int xb = x0 + e * DIL - PAD;
            f4 ww;
            ww.x = ((xb + 0 >= 0) & (xb + 0 < W_) ? rokf : 0.f) * __expf(-d2r[e].x);
            ww.y = ((xb + 1 >= 0) & (xb + 1 < W_) ? rokf : 0.f) * __expf(-d2r[e].y);
            ww.z = ((xb + 2 >= 0) & (xb + 2 < W_) ? rokf : 0.f) * __expf(-d2r[e].z);
            ww.w = ((xb + 3 >= 0) & (xb + 3 < W_) ? rokf : 0.f) * __expf(-d2r[e].w);
            w5[e] = ww;
            wsum.x += ww.x; wsum.y += ww.y; wsum.z += ww.z; wsum.w += ww.w;
        }

        // ---- accumulate all 24 channels for this row ----
#pragma unroll
        for (int c = 0; c < OUTC; ++c) {
            const float* __restrict__ ic = inpb + c * HW;
            float r[12];
#pragma unroll
            for (int k = 0; k < 3; ++k) {
                const f4 v = *(const f4*)(ic + roff + cbx[k]);
                r[4 * k + 0] = v.x; r[4 * k + 1] = v.y;
                r[4 * k + 2] = v.z; r[4 * k + 3] = v.w;
            }
#pragma unroll
            for (int e = 0; e < KS; ++e) {
                acc[c].x += w5[e].x * r[2 * e + 0];
                acc[c].y += w5[e].y * r[2 * e + 1];
                acc[c].z += w5[e].z * r[2 * e + 2];
                acc[c].w += w5[e].w * r[2 * e + 3];
            }
        }
    }

    // ---- normalize + store ----
    const f4 inv = make_float4(1.f / (wsum.x + 1e-8f), 1.f / (wsum.y + 1e-8f),
                               1.f / (wsum.z + 1e-8f), 1.f / (wsum.w + 1e-8f));
#pragma unroll
    for (int c = 0; c < OUTC; ++c) {
        f4 o;
        o.x = acc[c].x * inv.x; o.y = acc[c].y * inv.y;
        o.z = acc[c].z * inv.z; o.w = acc[c].w * inv.w;
        *(f4*)(outb + c * HW + crow) = o;
    }
}

extern "C" void kernel_launch(void* const* d_in, const int* in_sizes, int n_in,
                              void* d_out, int out_size, void* d_ws, size_t ws_size,
                              hipStream_t stream) {
    const float* inp = (const float*)d_in[0];   // (4,32,512,512) fp32
    const float* par = (const float*)d_in[1];   // (4,8,512,512) fp32
    float* out = (float*)d_out;                 // (4,24,512,512) fp32

    const int total = B_ * H_ * GPR;            // 262,144 threads (4 px each)
    dim3 block(256);
    dim3 grid(total / 256);                     // 1024 blocks
    bilateral_fused<<<grid, block, 0, stream>>>(inp, par, out);
}